// Round 4
// baseline (479.086 us; speedup 1.0000x reference)
//
#include <hip/hip_runtime.h>
#include <hip/hip_bf16.h>

// Problem constants (B=8, L=8192, C=256, PE=96, R=90, UP=4, OUT=256)
#define M_TOTAL 65536   // B*L
#define N_TOTAL 1024    // OUT*UP
#define K_TOTAL 448     // C + 2*PE
#define R_PE    90

typedef __bf16 bf16x8 __attribute__((ext_vector_type(8)));
typedef __bf16 bf16x4 __attribute__((ext_vector_type(4)));
typedef float  floatx4 __attribute__((ext_vector_type(4)));

// ---------------------------------------------------------------------------
// async global->LDS, 16B per lane. LDS dest = wave-uniform base + lane*16.
// ---------------------------------------------------------------------------
__device__ __forceinline__ void g2lds16(const void* g, void* l) {
    __builtin_amdgcn_global_load_lds(
        (const __attribute__((address_space(1))) void*)g,
        (__attribute__((address_space(3))) void*)l,
        16, 0, 0);
}

// ---------------------------------------------------------------------------
// cpe [3][96][90] -> cpeT [3][90][96] so per-row d-gathers are contiguous.
// ---------------------------------------------------------------------------
__global__ __launch_bounds__(256) void transpose_cpe(
    const float* __restrict__ cpe, float* __restrict__ cpeT)
{
    int i = blockIdx.x * 256 + threadIdx.x;
    if (i < 3 * 96 * R_PE) {
        int c = i / (96 * R_PE);
        int rem = i % (96 * R_PE);
        int d = rem / R_PE;
        int r = rem % R_PE;
        cpeT[((size_t)c * R_PE + r) * 96 + d] = cpe[i];
    }
}

// ---------------------------------------------------------------------------
// sub_w [1024,448] f32 -> bf16 (already B^T layout: N-major, K-contiguous)
// ---------------------------------------------------------------------------
__global__ __launch_bounds__(256) void convert_w(
    const float* __restrict__ w, __bf16* __restrict__ wb)
{
    int i = (blockIdx.x * 256 + threadIdx.x) * 4;
    if (i < N_TOTAL * K_TOTAL) {
        float4 v = *(const float4*)(w + i);
        bf16x4 o = { (__bf16)v.x, (__bf16)v.y, (__bf16)v.z, (__bf16)v.w };
        *(bf16x4*)(wb + i) = o;
    }
}

// ---------------------------------------------------------------------------
// pc_up: repeat_interleave(pc, 4, axis=1)
// ---------------------------------------------------------------------------
__global__ __launch_bounds__(256) void pc_up_kernel(
    const float* __restrict__ pc, float* __restrict__ out2)
{
    int e = blockIdx.x * 256 + threadIdx.x;
    if (e < M_TOTAL * 12) {
        int m = e / 12;
        int j = e % 3;
        out2[e] = pc[m * 3 + j];
    }
}

// ---------------------------------------------------------------------------
// In-GEMM PE tile: compute 8 bf16 PE values per thread-slot for K-tile TT.
// Slot s covers LDS chunk (r, cc); its GLOBAL k-chunk is cs = cc^(r&7)
// (matches the read-side swizzle), PE col p = (TT-4)*64 + cs*8 + e.
//   p <  96 : sin(pc . lff_w[p] + lff_b[p])
//   p >= 96 : bilinear const-PE at d = p-96, sum over 3 channels / sqrt(3)
// ---------------------------------------------------------------------------
template<int TT>
__device__ __forceinline__ void compute_pe_tile(
    int tid, int bm, const float* __restrict__ PC,
    const float* __restrict__ lff_w, const float* __restrict__ lff_b,
    const float* __restrict__ cpeT, bf16x8* pr)
{
    #pragma unroll
    for (int s = 0; s < 4; ++s) {
        const int idx = s * 256 + tid;
        const int r   = idx >> 3;
        const int cs  = (idx & 7) ^ (r & 7);
        const int m   = bm + r;
        const float p0 = PC[m * 3 + 0];
        const float p1 = PC[m * 3 + 1];
        const float p2 = PC[m * 3 + 2];
        const int pbase = (TT - 4) * 64 + cs * 8;
        float val[8];
        if (pbase < 96) {
            // ---- sin chunk: d = pbase..pbase+7 ----
            const float* wp = lff_w + pbase * 3;   // 24 consecutive floats
            const float* bp = lff_b + pbase;       // 8 consecutive floats
            float w24[24], b8[8];
            #pragma unroll
            for (int q = 0; q < 6; ++q) {
                float4 tv = *(const float4*)(wp + q * 4);
                w24[q*4] = tv.x; w24[q*4+1] = tv.y; w24[q*4+2] = tv.z; w24[q*4+3] = tv.w;
            }
            {
                float4 tv = *(const float4*)bp;
                b8[0]=tv.x; b8[1]=tv.y; b8[2]=tv.z; b8[3]=tv.w;
                tv = *(const float4*)(bp + 4);
                b8[4]=tv.x; b8[5]=tv.y; b8[6]=tv.z; b8[7]=tv.w;
            }
            #pragma unroll
            for (int e = 0; e < 8; ++e) {
                float a = fmaf(p2, w24[e*3+2],
                          fmaf(p1, w24[e*3+1],
                          fmaf(p0, w24[e*3+0], b8[e])));
                val[e] = __sinf(a);
            }
        } else {
            // ---- const-PE chunk: d = pbase-96 .. +7 ----
            const int d0 = pbase - 96;
            float a8[8] = {0.f,0.f,0.f,0.f,0.f,0.f,0.f,0.f};
            const float pch[3] = { p0, p1, p2 };
            #pragma unroll
            for (int c = 0; c < 3; ++c) {
                float ix = (pch[c] + 1.f) * 45.f - 0.5f;   // ((p+1)*R-1)*0.5
                float fl = floorf(ix);
                float w  = ix - fl;
                int   i0 = (int)fl;
                bool  ok0 = (i0 >= 0) && (i0 < R_PE);
                bool  ok1 = (i0 + 1 >= 0) && (i0 + 1 < R_PE);
                const float* t0 = cpeT + ((size_t)(c * R_PE + (ok0 ? i0     : 0))) * 96 + d0;
                const float* t1 = cpeT + ((size_t)(c * R_PE + (ok1 ? i0 + 1 : 0))) * 96 + d0;
                float m0 = ok0 ? (1.f - w) : 0.f;
                float m1 = ok1 ? w : 0.f;
                float4 u0 = *(const float4*)t0, u1 = *(const float4*)(t0 + 4);
                float4 v0 = *(const float4*)t1, v1 = *(const float4*)(t1 + 4);
                a8[0] = fmaf(m0, u0.x, fmaf(m1, v0.x, a8[0]));
                a8[1] = fmaf(m0, u0.y, fmaf(m1, v0.y, a8[1]));
                a8[2] = fmaf(m0, u0.z, fmaf(m1, v0.z, a8[2]));
                a8[3] = fmaf(m0, u0.w, fmaf(m1, v0.w, a8[3]));
                a8[4] = fmaf(m0, u1.x, fmaf(m1, v1.x, a8[4]));
                a8[5] = fmaf(m0, u1.y, fmaf(m1, v1.y, a8[5]));
                a8[6] = fmaf(m0, u1.z, fmaf(m1, v1.z, a8[6]));
                a8[7] = fmaf(m0, u1.w, fmaf(m1, v1.w, a8[7]));
            }
            #pragma unroll
            for (int e = 0; e < 8; ++e) val[e] = a8[e] * 0.57735026918962576f;
        }
        bf16x8 o = { (__bf16)val[0], (__bf16)val[1], (__bf16)val[2], (__bf16)val[3],
                     (__bf16)val[4], (__bf16)val[5], (__bf16)val[6], (__bf16)val[7] };
        pr[s] = o;
    }
}

// ---------------------------------------------------------------------------
// Mega GEMM: C[m,n] = sum_k xpe[m,k] * sub_w[n,k]; A built fully on the fly:
//   k in [0,256)  : bf16(X[m,k])       (reg-staged f32, swizzled ds_write)
//   k in [256,448): PE computed here   (sin + bilinear, swizzled ds_write)
// Sync = R3's proven drain pipeline (single tile in flight, 1 barrier/step).
// Epilogue: acc -> LDS (XOR-swizzled) -> coalesced 512B-contiguous float4
// stores with fused bias/lrelu/residual.
// ---------------------------------------------------------------------------
__global__ __launch_bounds__(256) void gemm_mega(
    const float* __restrict__ X,     // [65536, 256] f32
    const float* __restrict__ PC,    // [65536, 3]
    const float* __restrict__ lff_w, // [96,3]
    const float* __restrict__ lff_b, // [96]
    const float* __restrict__ cpeT,  // [3,90,96]
    const __bf16* __restrict__ Bw,   // [1024, 448] bf16
    const float* __restrict__ bias,  // [1024]
    float* __restrict__ out)         // x_up part of d_out
{
    __shared__ __attribute__((aligned(16))) char smem[65536];
    // K-loop view: As[2] at smem+0, Bs[2] at smem+32768 (16 KB each)
    // Epilogue view: Cs = 128x128 f32 (all 64 KB)
    __bf16* AsBase = (__bf16*)smem;
    __bf16* BsBase = (__bf16*)(smem + 32768);
    float*  Cs     = (float*)smem;

    const int tid  = threadIdx.x;
    const int wave = tid >> 6;
    const int lane = tid & 63;
    const int quad = lane >> 4;
    const int l16  = lane & 15;
    const int wm   = (wave >> 1) * 64;
    const int wn   = (wave & 1) * 64;

    // XCD-aware swizzle: 8 N-blocks of one M-tile land consecutively on 1 XCD.
    const unsigned bx = blockIdx.x;
    const int bm = (int)(((bx & 7u) * 64u + (bx >> 6)) * 128u);
    const int bn = (int)(((bx >> 3) & 7u) * 128u);

    floatx4 acc[4][4];
    #pragma unroll
    for (int i = 0; i < 4; ++i)
        #pragma unroll
        for (int j = 0; j < 4; ++j)
            acc[i][j] = (floatx4){0.f, 0.f, 0.f, 0.f};

    float4 xr[2][8];   // X staging regs, tile-parity sets (static indexing)
    bf16x8 pr[4];      // PE staging regs (consumed same step)

    auto stageB = [&](int buf, int tt) {            // 4 x g2lds16
        const int kt = tt * 64;
        #pragma unroll
        for (int s = 0; s < 4; ++s) {
            const int idx = s * 256 + tid;
            const int r   = idx >> 3;
            const int cs  = (idx & 7) ^ (r & 7);    // pre-swizzled source chunk
            g2lds16(Bw + (size_t)(bn + r) * K_TOTAL + kt + cs * 8,
                    BsBase + (size_t)buf * 8192 + (size_t)(s * 256 + wave * 64) * 8);
        }
    };
    auto loadX = [&](float4* xr8, int tt) {         // tt<4, 8 x dwordx4 -> regs
        const int kt = tt * 64;
        #pragma unroll
        for (int s = 0; s < 4; ++s) {
            const int idx = s * 256 + tid;
            const int r   = idx >> 3;
            const int cs  = (idx & 7) ^ (r & 7);    // swizzled source col
            const float* src = X + (size_t)(bm + r) * 256 + kt + cs * 8;
            xr8[s * 2]     = *(const float4*)src;
            xr8[s * 2 + 1] = *(const float4*)(src + 4);
        }
    };
    auto writeX = [&](int buf, const float4* xr8) { // cvt + 4 x ds_write_b128
        #pragma unroll
        for (int s = 0; s < 4; ++s) {
            const int idx = s * 256 + tid;          // linear LDS slot
            float4 a = xr8[s * 2];
            float4 b = xr8[s * 2 + 1];
            bf16x8 o = { (__bf16)a.x, (__bf16)a.y, (__bf16)a.z, (__bf16)a.w,
                         (__bf16)b.x, (__bf16)b.y, (__bf16)b.z, (__bf16)b.w };
            *(bf16x8*)(AsBase + (size_t)buf * 8192 + (size_t)idx * 8) = o;
        }
    };
    auto writePE = [&](int buf) {                   // 4 x ds_write_b128
        #pragma unroll
        for (int s = 0; s < 4; ++s) {
            const int idx = s * 256 + tid;
            *(bf16x8*)(AsBase + (size_t)buf * 8192 + (size_t)idx * 8) = pr[s];
        }
    };

    // ---- prologue: stage tile 0 fully, publish ----
    loadX(xr[0], 0);
    stageB(0, 0);
    asm volatile("s_waitcnt vmcnt(0)" ::: "memory");
    writeX(0, xr[0]);
    asm volatile("s_waitcnt lgkmcnt(0)" ::: "memory");
    __builtin_amdgcn_s_barrier();

    #pragma unroll
    for (int t = 0; t < 7; ++t) {
        const int cur = t & 1;

        // issue tile t+1 into buf cur^1 (overlaps with compute below)
        if (t < 3) {
            loadX(xr[(t + 1) & 1], t + 1);
            stageB(cur ^ 1, t + 1);
        } else if (t < 6) {
            stageB(cur ^ 1, t + 1);
            if (t == 3) compute_pe_tile<4>(tid, bm, PC, lff_w, lff_b, cpeT, pr);
            if (t == 4) compute_pe_tile<5>(tid, bm, PC, lff_w, lff_b, cpeT, pr);
            if (t == 5) compute_pe_tile<6>(tid, bm, PC, lff_w, lff_b, cpeT, pr);
        }

        // compute on buf cur
        const __bf16* Ac = AsBase + (size_t)cur * 8192;
        const __bf16* Bc = BsBase + (size_t)cur * 8192;
        #pragma unroll
        for (int s = 0; s < 2; ++s) {
            bf16x8 af[4], bfr[4];
            #pragma unroll
            for (int i = 0; i < 4; ++i) {
                const int row = wm + i * 16 + l16;
                const int ch  = (s * 4 + quad) ^ (row & 7);   // read-side swizzle
                af[i] = *(const bf16x8*)(Ac + row * 64 + ch * 8);
            }
            #pragma unroll
            for (int j = 0; j < 4; ++j) {
                const int row = wn + j * 16 + l16;
                const int ch  = (s * 4 + quad) ^ (row & 7);
                bfr[j] = *(const bf16x8*)(Bc + row * 64 + ch * 8);
            }
            __builtin_amdgcn_s_setprio(1);
            #pragma unroll
            for (int i = 0; i < 4; ++i)
                #pragma unroll
                for (int j = 0; j < 4; ++j)
                    acc[i][j] = __builtin_amdgcn_mfma_f32_16x16x32_bf16(
                        af[i], bfr[j], acc[i][j], 0, 0, 0);
            __builtin_amdgcn_s_setprio(0);
        }

        // drain tile t+1 loads (hidden under compute), publish, swap
        if (t < 6) {
            asm volatile("s_waitcnt vmcnt(0)" ::: "memory");
            if (t < 3) writeX(cur ^ 1, xr[(t + 1) & 1]);
            else       writePE(cur ^ 1);
            asm volatile("s_waitcnt lgkmcnt(0)" ::: "memory");
            __builtin_amdgcn_s_barrier();   // publishes t+1; frees buf cur
        }
    }

    // ---- epilogue: acc -> LDS (swizzled) -> coalesced stores ----
    __syncthreads();   // all MFMA LDS reads done; smem becomes Cs

    #pragma unroll
    for (int i = 0; i < 4; ++i)
        #pragma unroll
        for (int j = 0; j < 4; ++j)
            #pragma unroll
            for (int r = 0; r < 4; ++r) {
                const int mloc = wm + i * 16 + quad * 4 + r;
                const int nloc = wn + j * 16 + l16;
                // XOR-swizzle n by (m>>2)&3 -> 32-bank spread, 2-way max
                Cs[mloc * 128 + (nloc ^ (((mloc >> 2) & 3) << 3))] = acc[i][j][r];
            }
    __syncthreads();

    const float gain = 0.047245559126153576f;     // 1/sqrt(448)
    const float inv_sqrt2 = 0.70710678118654752f;
    const int u    = bn >> 8;
    const int ocol = bn & 255;
    const int erow = tid >> 5;          // 0..7
    const int ec   = (tid & 31) * 4;    // float chunk in row, 0..124

    #pragma unroll
    for (int g = 0; g < 16; ++g) {
        const int row = g * 8 + erow;
        const int xsw = ((row >> 2) & 3) << 3;
        floatx4 v = *(const floatx4*)(Cs + row * 128 + (ec ^ xsw));
        const int m = bm + row;
        float4 bsv = *(const float4*)(bias + bn + ec);
        float4 res = *(const float4*)(X + (size_t)m * 256 + ocol + ec);
        float4 o;
        { float y = fmaf(v[0], gain, bsv.x); float a = (y >= 0.f) ? y : 0.2f * y;
          o.x = fmaf(res.x, inv_sqrt2, a); }
        { float y = fmaf(v[1], gain, bsv.y); float a = (y >= 0.f) ? y : 0.2f * y;
          o.y = fmaf(res.y, inv_sqrt2, a); }
        { float y = fmaf(v[2], gain, bsv.z); float a = (y >= 0.f) ? y : 0.2f * y;
          o.z = fmaf(res.z, inv_sqrt2, a); }
        { float y = fmaf(v[3], gain, bsv.w); float a = (y >= 0.f) ? y : 0.2f * y;
          o.w = fmaf(res.w, inv_sqrt2, a); }
        *(float4*)(out + ((size_t)(m * 4 + u)) * 256 + ocol + ec) = o;
    }
}

// ---------------------------------------------------------------------------
extern "C" void kernel_launch(void* const* d_in, const int* in_sizes, int n_in,
                              void* d_out, int out_size, void* d_ws, size_t ws_size,
                              hipStream_t stream) {
    const float* X      = (const float*)d_in[0];  // [8,8192,256]
    const float* pc     = (const float*)d_in[1];  // [8,8192,3]
    const float* lff_w  = (const float*)d_in[2];  // [96,3]
    const float* lff_b  = (const float*)d_in[3];  // [96]
    const float* cpe    = (const float*)d_in[4];  // [3,96,90]
    const float* sub_w  = (const float*)d_in[5];  // [1024,448]
    const float* sub_b  = (const float*)d_in[6];  // [1024]

    float* out    = (float*)d_out;                       // x_up: 67108864 floats
    float* out_pc = out + (size_t)M_TOTAL * 4 * 256;     // pc_up: 786432 floats

    // workspace: sub_w bf16 [1024,448], cpeT f32 [3,90,96]
    __bf16* wb   = (__bf16*)d_ws;
    float*  cpeT = (float*)((char*)d_ws + (size_t)N_TOTAL * K_TOTAL * 2);

    convert_w    <<<448,  256, 0, stream>>>(sub_w, wb);
    transpose_cpe<<<102,  256, 0, stream>>>(cpe, cpeT);
    pc_up_kernel <<<3072, 256, 0, stream>>>(pc, out_pc);
    gemm_mega    <<<4096, 256, 0, stream>>>(X, pc, lff_w, lff_b, cpeT, wb, sub_b, out);
}